// Round 2
// baseline (2407.520 us; speedup 1.0000x reference)
//
#include <hip/hip_runtime.h>

#define N_NODES 50000
#define E1N 1600000
#define M_PAIRS 200000
#define E2N 3200000
#define P_OUT 20000
#define EPSF 1e-5f

#define RED_BLOCKS 512

// ---------------- stats offsets within stats buffer (floats) ----------------
#define S0_SUM   0
#define S0_SQ    32
#define S_A0     64
#define S_B0     96
#define S_B0ROW  128
#define S1_SUM   160
#define S1_SQ    192
#define S_A1     224
#define S_B1     256
#define S_CNT    288   // int
#define S_ZC0    320
#define S_ZC1    352
#define S3_SUM   384
#define S3_SQ    416
#define S_A3     448
#define S_B3     480
#define S_TOTAL  512

__device__ __forceinline__ void f4add(float4& a, const float4 b) {
    a.x += b.x; a.y += b.y; a.z += b.z; a.w += b.w;
}

// block-level reduce of per-thread float4 partials (feature group = (tid&7)*4),
// then one atomic per feature per block
__device__ __forceinline__ void stats_block_reduce(float4 s, float4 q,
                                                   float* __restrict__ sum,
                                                   float* __restrict__ sumsq) {
    __shared__ float4 ss[256], sq[256];
    int tid = threadIdx.x;
    ss[tid] = s; sq[tid] = q;
    __syncthreads();
    #pragma unroll
    for (int st = 128; st >= 8; st >>= 1) {
        if (tid < st) { f4add(ss[tid], ss[tid + st]); f4add(sq[tid], sq[tid + st]); }
        __syncthreads();
    }
    if (tid < 8) {
        int base = tid * 4;
        float4 fs = ss[tid], fq = sq[tid];
        atomicAdd(&sum[base + 0], fs.x);
        atomicAdd(&sum[base + 1], fs.y);
        atomicAdd(&sum[base + 2], fs.z);
        atomicAdd(&sum[base + 3], fs.w);
        atomicAdd(&sumsq[base + 0], fq.x);
        atomicAdd(&sumsq[base + 1], fq.y);
        atomicAdd(&sumsq[base + 2], fq.z);
        atomicAdd(&sumsq[base + 3], fq.w);
    }
}

// gather embedding rows (float4 granularity), store e, accumulate stats
__global__ void k_embed_stats(const float* __restrict__ emb, const int* __restrict__ x,
                              float* __restrict__ e, float* __restrict__ sum,
                              float* __restrict__ sumsq, int n) {
    long n4 = (long)n * 8;  // float4 count
    float4 s = {0,0,0,0}, q = {0,0,0,0};
    float4* e4 = (float4*)e;
    long stride = (long)gridDim.x * 256;
    for (long i = (long)blockIdx.x * 256 + threadIdx.x; i < n4; i += stride) {
        int node = (int)(i >> 3), fg = ((int)i & 7) * 4;
        int xr = x[node];
        float4 v = *(const float4*)&emb[(long)xr * 32 + fg];
        e4[i] = v;
        s.x += v.x; s.y += v.y; s.z += v.z; s.w += v.w;
        q.x += v.x * v.x; q.y += v.y * v.y; q.z += v.z * v.z; q.w += v.w * v.w;
    }
    stats_block_reduce(s, q, sum, sumsq);
}

// per-feature sum/sumsq over [n,32] buffer
__global__ void k_stats32(const float* __restrict__ g, float* __restrict__ sum,
                          float* __restrict__ sumsq, long n32) {
    long n4 = n32 >> 2;
    const float4* g4 = (const float4*)g;
    float4 s = {0,0,0,0}, q = {0,0,0,0};
    long stride = (long)gridDim.x * 256;
    for (long i = (long)blockIdx.x * 256 + threadIdx.x; i < n4; i += stride) {
        float4 v = g4[i];
        s.x += v.x; s.y += v.y; s.z += v.z; s.w += v.w;
        q.x += v.x * v.x; q.y += v.y * v.y; q.z += v.z * v.z; q.w += v.w * v.w;
    }
    stats_block_reduce(s, q, sum, sumsq);
}

// GraphNorm -> per-feature affine A,B.  y = A*x + B
__global__ void k_affine32(const float* __restrict__ sum, const float* __restrict__ sumsq,
                           const float* __restrict__ w, const float* __restrict__ b,
                           const float* __restrict__ ms, float invN,
                           float* __restrict__ A, float* __restrict__ B) {
    int f = threadIdx.x;  // 32 threads
    float mean = sum[f] * invN;
    float c = ms[f] * mean;
    float var = sumsq[f] * invN - 2.f * c * mean + c * c;
    float rs = rsqrtf(var + EPSF);
    A[f] = w[f] * rs;
    B[f] = b[f] - w[f] * rs * c;
}

// fold affine shift through matmul: brow[o] = sum_f B[f]*W[f][o]
__global__ void k_foldbias(const float* __restrict__ B, const float* __restrict__ W,
                           float* __restrict__ brow) {
    int o = threadIdx.x;  // 32 threads
    float s = 0.f;
    #pragma unroll
    for (int f = 0; f < 32; f++) s += B[f] * W[f * 32 + o];
    brow[o] = s;
}

// t[i][o] = sum_f (A[f]*e[i][f]) * W[f][o] + brow[o]   (A/brow may be null)
__global__ void k_mm32(const float* __restrict__ e, const float* __restrict__ W,
                       const float* __restrict__ A, const float* __restrict__ brow,
                       float* __restrict__ t, int n) {
    __shared__ float Wp[32][32];
    __shared__ float rows[8][32];
    int lt = threadIdx.x;
    for (int k = lt; k < 1024; k += 256) {
        int f = k >> 5;
        Wp[f][k & 31] = (A ? A[f] : 1.f) * W[k];
    }
    int nl = lt >> 5, o = lt & 31;
    int node = blockIdx.x * 8 + nl;
    if (node < n) rows[nl][o] = e[node * 32 + o];
    __syncthreads();
    if (node < n) {
        float acc = brow ? brow[o] : 0.f;
        #pragma unroll
        for (int f = 0; f < 32; f++) acc += rows[nl][f] * Wp[f][o];
        t[node * 32 + o] = acc;
    }
}

__global__ void k_deg(const int* __restrict__ col, float* __restrict__ deg, int ne) {
    int i = blockIdx.x * 256 + threadIdx.x;
    if (i < ne) atomicAdd(&deg[col[i]], 1.f);
}

__global__ void k_dinv(float* __restrict__ deg, int n) {  // in place: deg -> rsqrt(deg+1)
    int i = blockIdx.x * 256 + threadIdx.x;
    if (i < n) deg[i] = rsqrtf(deg[i] + 1.f);
}

// scatter-add: agg[col][fg..fg+3] += t[row][fg..fg+3] * dinv[row]*dinv[col]
// one thread per (edge, 4-feature group)
__global__ void k_agg(const int* __restrict__ row, const int* __restrict__ col,
                      const float* __restrict__ t, const float* __restrict__ dinv,
                      float* __restrict__ agg, int ne) {
    long idx = (long)blockIdx.x * 256 + threadIdx.x;
    if (idx >= (long)ne * 8) return;
    int e = (int)(idx >> 3), fg = ((int)idx & 7) * 4;
    int r = row[e], c = col[e];
    float coef = dinv[r] * dinv[c];
    float4 v = *(const float4*)&t[(long)r * 32 + fg];
    float* dst = &agg[(long)c * 32 + fg];
    atomicAdd(dst + 0, v.x * coef);
    atomicAdd(dst + 1, v.y * coef);
    atomicAdd(dst + 2, v.z * coef);
    atomicAdd(dst + 3, v.w * coef);
}

// g += self-loop term + conv bias (float4)
__global__ void k_self_bias(float* __restrict__ agg, const float* __restrict__ t,
                            const float* __restrict__ dinv, const float* __restrict__ bias,
                            int n) {
    long idx = (long)blockIdx.x * 256 + threadIdx.x;
    if (idx >= (long)n * 8) return;
    int i = (int)(idx >> 3), fg = ((int)idx & 7) * 4;
    float d = dinv[i];
    float4 v = *(const float4*)&t[idx * 4];
    float4 b = *(const float4*)&bias[fg];
    float4* dst = (float4*)&agg[idx * 4];
    float4 a = *dst;
    a.x += v.x * d * d + b.x;
    a.y += v.y * d * d + b.y;
    a.z += v.z * d * d + b.z;
    a.w += v.w * d * d + b.w;
    *dst = a;
}

__global__ void k_affine_relu(const float* __restrict__ g, const float* __restrict__ A,
                              const float* __restrict__ B, float* __restrict__ h, long n32) {
    long idx = (long)blockIdx.x * 256 + threadIdx.x;
    if (idx >= (n32 >> 2)) return;
    int fg = ((int)idx & 7) * 4;
    float4 v = *(const float4*)&g[idx * 4];
    float4 a = *(const float4*)&A[fg];
    float4 b = *(const float4*)&B[fg];
    float4 r;
    r.x = fmaxf(a.x * v.x + b.x, 0.f);
    r.y = fmaxf(a.y * v.y + b.y, 0.f);
    r.z = fmaxf(a.z * v.z + b.z, 0.f);
    r.w = fmaxf(a.w * v.w + b.w, 0.f);
    *(float4*)&h[idx * 4] = r;
}

__global__ void k_mask(const int* __restrict__ pos2, int* __restrict__ mask, int p) {
    int i = blockIdx.x * 256 + threadIdx.x;
    if (i < p) mask[pos2[i]] = 1;
}

__global__ void k_count(const int* __restrict__ mask, int* __restrict__ cnt, int m) {
    __shared__ int sd[256];
    int idx = blockIdx.x * 256 + threadIdx.x;
    sd[threadIdx.x] = (idx < m) ? mask[idx] : 0;
    __syncthreads();
    for (int s = 128; s > 0; s >>= 1) {
        if (threadIdx.x < s) sd[threadIdx.x] += sd[threadIdx.x + s];
        __syncthreads();
    }
    if (threadIdx.x == 0) atomicAdd(cnt, sd[0]);
}

// z has only two distinct rows (mask 0/1); compute zc{0,1}[o] = z{0,1} @ c2_W[32:48]
__global__ void k_zcalc(const float* __restrict__ emb2, const float* __restrict__ w,
                        const float* __restrict__ b, const float* __restrict__ ms,
                        const int* __restrict__ cnt, const float* __restrict__ c2W,
                        float* __restrict__ zc0, float* __restrict__ zc1) {
    __shared__ float z0[16], z1[16];
    int t = threadIdx.x;  // 32 threads
    const float Mf = (float)M_PAIRS;
    if (t < 16) {
        float e0 = emb2[t], e1 = emb2[16 + t];
        float c1f = (float)(*cnt);
        float mean = (c1f * e1 + (Mf - c1f) * e0) / Mf;
        float c = ms[t] * mean;
        float d0 = e0 - c, d1 = e1 - c;
        float var = (c1f * d1 * d1 + (Mf - c1f) * d0 * d0) / Mf;
        float rs = rsqrtf(var + EPSF);
        z0[t] = w[t] * d0 * rs + b[t];
        z1[t] = w[t] * d1 * rs + b[t];
    }
    __syncthreads();
    float s0 = 0.f, s1 = 0.f;
    #pragma unroll
    for (int f = 0; f < 16; f++) {
        float wv = c2W[(32 + f) * 32 + t];
        s0 += z0[f] * wv;
        s1 += z1[f] * wv;
    }
    zc0[t] = s0;
    zc1[t] = s1;
}

// t2[j][fg..] = hw[a][fg..] + hw[b][fg..] + zc_{mask[j]}[fg..]
__global__ void k_t2(const float* __restrict__ hw, const int* __restrict__ pos1,
                     const int* __restrict__ mask, const float* __restrict__ zc0,
                     const float* __restrict__ zc1, float* __restrict__ t2, int m) {
    long idx = (long)blockIdx.x * 256 + threadIdx.x;
    if (idx >= (long)m * 8) return;
    int j = (int)(idx >> 3), fg = ((int)idx & 7) * 4;
    int a = pos1[2 * j], b = pos1[2 * j + 1];
    const float* zc = mask[j] ? zc1 : zc0;
    float4 va = *(const float4*)&hw[(long)a * 32 + fg];
    float4 vb = *(const float4*)&hw[(long)b * 32 + fg];
    float4 vz = *(const float4*)&zc[fg];
    float4 r;
    r.x = va.x + vb.x + vz.x;
    r.y = va.y + vb.y + vz.y;
    r.z = va.z + vb.z + vz.z;
    r.w = va.w + vb.w + vz.w;
    *(float4*)&t2[idx * 4] = r;
}

// out[k] = relu(A*g2[pos2[k]]+B) . predW + predb
__global__ void k_pred(const float* __restrict__ g2, const int* __restrict__ pos2,
                       const float* __restrict__ A, const float* __restrict__ B,
                       const float* __restrict__ predW, const float* __restrict__ predb,
                       float* __restrict__ out, int p) {
    int k = blockIdx.x * 256 + threadIdx.x;
    if (k >= p) return;
    int j = pos2[k];
    float s = predb[0];
    #pragma unroll
    for (int o = 0; o < 32; o++)
        s += fmaxf(A[o] * g2[(long)j * 32 + o] + B[o], 0.f) * predW[o];
    out[k] = s;
}

extern "C" void kernel_launch(void* const* d_in, const int* in_sizes, int n_in,
                              void* d_out, int out_size, void* d_ws, size_t ws_size,
                              hipStream_t stream) {
    const int*   x      = (const int*)d_in[0];
    const int*   e1row  = (const int*)d_in[1];
    const int*   e1col  = e1row + E1N;
    const int*   e2row  = (const int*)d_in[2];
    const int*   e2col  = e2row + E2N;
    const int*   pos1   = (const int*)d_in[3];
    const int*   pos2   = (const int*)d_in[4];
    const float* emb1   = (const float*)d_in[5];
    const float* gn0_w  = (const float*)d_in[6];
    const float* gn0_b  = (const float*)d_in[7];
    const float* gn0_ms = (const float*)d_in[8];
    const float* c1_W   = (const float*)d_in[9];
    const float* c1_b   = (const float*)d_in[10];
    const float* gn1_w  = (const float*)d_in[11];
    const float* gn1_b  = (const float*)d_in[12];
    const float* gn1_ms = (const float*)d_in[13];
    const float* emb2   = (const float*)d_in[14];
    const float* gn2_w  = (const float*)d_in[15];
    const float* gn2_b  = (const float*)d_in[16];
    const float* gn2_ms = (const float*)d_in[17];
    const float* c2_W   = (const float*)d_in[18];
    const float* c2_b   = (const float*)d_in[19];
    const float* gn3_w  = (const float*)d_in[20];
    const float* gn3_b  = (const float*)d_in[21];
    const float* gn3_ms = (const float*)d_in[22];
    const float* predW  = (const float*)d_in[23];
    const float* predb  = (const float*)d_in[24];
    float* out = (float*)d_out;

    // ---------------- workspace arena (floats) ----------------
    float* W = (float*)d_ws;
    const size_t N32 = (size_t)N_NODES * 32;   // 1,600,000
    const size_t M32 = (size_t)M_PAIRS * 32;   // 6,400,000
    float* e    = W;                 // N32   (reused as hw later)
    float* t    = e + N32;           // N32
    float* agg  = t + N32;           // N32
    float* h1   = agg + N32;         // N32
    float* t2   = h1 + N32;          // M32
    float* agg2 = t2 + M32;          // M32
    float* d1   = agg2 + M32;        // N
    float* d2   = d1 + N_NODES;      // M
    int*   mask = (int*)(d2 + M_PAIRS);  // M ints
    float* st   = (float*)(mask + M_PAIRS);  // S_TOTAL floats
    float* hw   = e;  // alias: e is dead after k_mm32 for conv1

    // ---------------- zero accumulators ----------------
    hipMemsetAsync(agg,  0, N32 * 4, stream);
    hipMemsetAsync(agg2, 0, M32 * 4, stream);
    hipMemsetAsync(d1,   0, N_NODES * 4, stream);
    hipMemsetAsync(d2,   0, M_PAIRS * 4, stream);
    hipMemsetAsync(mask, 0, M_PAIRS * 4, stream);
    hipMemsetAsync(st,   0, S_TOTAL * 4, stream);

    auto cdiv = [](long a, long b) { return (int)((a + b - 1) / b); };
    const float invN = 1.f / (float)N_NODES;
    const float invM = 1.f / (float)M_PAIRS;

    // ---- stage 0: embedding + gn0 stats ----
    k_embed_stats<<<RED_BLOCKS, 256, 0, stream>>>(emb1, x, e, st + S0_SUM, st + S0_SQ, N_NODES);
    k_deg<<<cdiv(E1N, 256), 256, 0, stream>>>(e1col, d1, E1N);
    k_dinv<<<cdiv(N_NODES, 256), 256, 0, stream>>>(d1, N_NODES);
    k_affine32<<<1, 32, 0, stream>>>(st + S0_SUM, st + S0_SQ, gn0_w, gn0_b, gn0_ms, invN,
                                     st + S_A0, st + S_B0);
    k_foldbias<<<1, 32, 0, stream>>>(st + S_B0, c1_W, st + S_B0ROW);

    // ---- conv1: t = gn0(e) @ c1_W ----
    k_mm32<<<cdiv(N_NODES, 8), 256, 0, stream>>>(e, c1_W, st + S_A0, st + S_B0ROW, t, N_NODES);
    k_agg<<<cdiv((long)E1N * 8, 256), 256, 0, stream>>>(e1row, e1col, t, d1, agg, E1N);
    k_self_bias<<<cdiv((long)N_NODES * 8, 256), 256, 0, stream>>>(agg, t, d1, c1_b, N_NODES);

    // ---- gn1 + relu -> h1 ----
    k_stats32<<<RED_BLOCKS, 256, 0, stream>>>(agg, st + S1_SUM, st + S1_SQ, (long)N32);
    k_affine32<<<1, 32, 0, stream>>>(st + S1_SUM, st + S1_SQ, gn1_w, gn1_b, gn1_ms, invN,
                                     st + S_A1, st + S_B1);
    k_affine_relu<<<cdiv((long)N32 / 4, 256), 256, 0, stream>>>(agg, st + S_A1, st + S_B1, h1, (long)N32);

    // ---- mask / z path ----
    k_mask<<<cdiv(P_OUT, 256), 256, 0, stream>>>(pos2, mask, P_OUT);
    k_count<<<cdiv(M_PAIRS, 256), 256, 0, stream>>>(mask, (int*)(st + S_CNT), M_PAIRS);
    k_zcalc<<<1, 32, 0, stream>>>(emb2, gn2_w, gn2_b, gn2_ms, (const int*)(st + S_CNT),
                                  c2_W, st + S_ZC0, st + S_ZC1);

    // ---- conv2 input: hw = h1 @ c2_W[0:32]; t2 = hw[a]+hw[b]+zc ----
    k_mm32<<<cdiv(N_NODES, 8), 256, 0, stream>>>(h1, c2_W, nullptr, nullptr, hw, N_NODES);
    k_t2<<<cdiv((long)M_PAIRS * 8, 256), 256, 0, stream>>>(hw, pos1, mask, st + S_ZC0, st + S_ZC1, t2, M_PAIRS);

    // ---- conv2 aggregation ----
    k_deg<<<cdiv(E2N, 256), 256, 0, stream>>>(e2col, d2, E2N);
    k_dinv<<<cdiv(M_PAIRS, 256), 256, 0, stream>>>(d2, M_PAIRS);
    k_agg<<<cdiv((long)E2N * 8, 256), 256, 0, stream>>>(e2row, e2col, t2, d2, agg2, E2N);
    k_self_bias<<<cdiv((long)M_PAIRS * 8, 256), 256, 0, stream>>>(agg2, t2, d2, c2_b, M_PAIRS);

    // ---- gn3 + relu + predict ----
    k_stats32<<<RED_BLOCKS, 256, 0, stream>>>(agg2, st + S3_SUM, st + S3_SQ, (long)M32);
    k_affine32<<<1, 32, 0, stream>>>(st + S3_SUM, st + S3_SQ, gn3_w, gn3_b, gn3_ms, invM,
                                     st + S_A3, st + S_B3);
    k_pred<<<cdiv(P_OUT, 256), 256, 0, stream>>>(agg2, pos2, st + S_A3, st + S_B3,
                                                 predW, predb, out, P_OUT);
}

// Round 4
// 973.714 us; speedup vs baseline: 2.4725x; 2.4725x over previous
//
#include <hip/hip_runtime.h>

#define N_NODES 50000
#define E1N 1600000
#define M_PAIRS 200000
#define E2N 3200000
#define P_OUT 20000
#define EPSF 1e-5f

#define RED_BLOCKS 512

// ---------------- stats offsets within stats buffer (floats) ----------------
#define S0_SUM   0
#define S0_SQ    32
#define S_A0     64
#define S_B0     96
#define S_B0ROW  128
#define S1_SUM   160
#define S1_SQ    192
#define S_A1     224
#define S_B1     256
#define S_CNT    288   // int
#define S_ZC0    320
#define S_ZC1    352
#define S3_SUM   384
#define S3_SQ    416
#define S_A3     448
#define S_B3     480
#define S_TOTAL  512

__device__ __forceinline__ void f4add(float4& a, const float4 b) {
    a.x += b.x; a.y += b.y; a.z += b.z; a.w += b.w;
}

// block-level reduce of per-thread float4 partials (feature group = (tid&7)*4),
// then one atomic per feature per block
__device__ __forceinline__ void stats_block_reduce(float4 s, float4 q,
                                                   float* __restrict__ sum,
                                                   float* __restrict__ sumsq) {
    __shared__ float4 ss[256], sq[256];
    int tid = threadIdx.x;
    ss[tid] = s; sq[tid] = q;
    __syncthreads();
    #pragma unroll
    for (int st = 128; st >= 8; st >>= 1) {
        if (tid < st) { f4add(ss[tid], ss[tid + st]); f4add(sq[tid], sq[tid + st]); }
        __syncthreads();
    }
    if (tid < 8) {
        int base = tid * 4;
        float4 fs = ss[tid], fq = sq[tid];
        atomicAdd(&sum[base + 0], fs.x);
        atomicAdd(&sum[base + 1], fs.y);
        atomicAdd(&sum[base + 2], fs.z);
        atomicAdd(&sum[base + 3], fs.w);
        atomicAdd(&sumsq[base + 0], fq.x);
        atomicAdd(&sumsq[base + 1], fq.y);
        atomicAdd(&sumsq[base + 2], fq.z);
        atomicAdd(&sumsq[base + 3], fq.w);
    }
}

// gather embedding rows (float4 granularity), store e, accumulate stats
__global__ void k_embed_stats(const float* __restrict__ emb, const int* __restrict__ x,
                              float* __restrict__ e, float* __restrict__ sum,
                              float* __restrict__ sumsq, int n) {
    long n4 = (long)n * 8;  // float4 count
    float4 s = {0,0,0,0}, q = {0,0,0,0};
    float4* e4 = (float4*)e;
    long stride = (long)gridDim.x * 256;
    for (long i = (long)blockIdx.x * 256 + threadIdx.x; i < n4; i += stride) {
        int node = (int)(i >> 3), fg = ((int)i & 7) * 4;
        int xr = x[node];
        float4 v = *(const float4*)&emb[(long)xr * 32 + fg];
        e4[i] = v;
        s.x += v.x; s.y += v.y; s.z += v.z; s.w += v.w;
        q.x += v.x * v.x; q.y += v.y * v.y; q.z += v.z * v.z; q.w += v.w * v.w;
    }
    stats_block_reduce(s, q, sum, sumsq);
}

// per-feature sum/sumsq over [n,32] buffer
__global__ void k_stats32(const float* __restrict__ g, float* __restrict__ sum,
                          float* __restrict__ sumsq, long n32) {
    long n4 = n32 >> 2;
    const float4* g4 = (const float4*)g;
    float4 s = {0,0,0,0}, q = {0,0,0,0};
    long stride = (long)gridDim.x * 256;
    for (long i = (long)blockIdx.x * 256 + threadIdx.x; i < n4; i += stride) {
        float4 v = g4[i];
        s.x += v.x; s.y += v.y; s.z += v.z; s.w += v.w;
        q.x += v.x * v.x; q.y += v.y * v.y; q.z += v.z * v.z; q.w += v.w * v.w;
    }
    stats_block_reduce(s, q, sum, sumsq);
}

// GraphNorm -> per-feature affine A,B.  y = A*x + B
__global__ void k_affine32(const float* __restrict__ sum, const float* __restrict__ sumsq,
                           const float* __restrict__ w, const float* __restrict__ b,
                           const float* __restrict__ ms, float invN,
                           float* __restrict__ A, float* __restrict__ B) {
    int f = threadIdx.x;  // 32 threads
    float mean = sum[f] * invN;
    float c = ms[f] * mean;
    float var = sumsq[f] * invN - 2.f * c * mean + c * c;
    float rs = rsqrtf(var + EPSF);
    A[f] = w[f] * rs;
    B[f] = b[f] - w[f] * rs * c;
}

// fold affine shift through matmul: brow[o] = sum_f B[f]*W[f][o]
__global__ void k_foldbias(const float* __restrict__ B, const float* __restrict__ W,
                           float* __restrict__ brow) {
    int o = threadIdx.x;  // 32 threads
    float s = 0.f;
    #pragma unroll
    for (int f = 0; f < 32; f++) s += B[f] * W[f * 32 + o];
    brow[o] = s;
}

// t[i][o] = sum_f (A[f]*e[i][f]) * W[f][o] + brow[o]   (A/brow may be null)
__global__ void k_mm32(const float* __restrict__ e, const float* __restrict__ W,
                       const float* __restrict__ A, const float* __restrict__ brow,
                       float* __restrict__ t, int n) {
    __shared__ float Wp[32][32];
    __shared__ float rows[8][32];
    int lt = threadIdx.x;
    for (int k = lt; k < 1024; k += 256) {
        int f = k >> 5;
        Wp[f][k & 31] = (A ? A[f] : 1.f) * W[k];
    }
    int nl = lt >> 5, o = lt & 31;
    int node = blockIdx.x * 8 + nl;
    if (node < n) rows[nl][o] = e[node * 32 + o];
    __syncthreads();
    if (node < n) {
        float acc = brow ? brow[o] : 0.f;
        #pragma unroll
        for (int f = 0; f < 32; f++) acc += rows[nl][f] * Wp[f][o];
        t[node * 32 + o] = acc;
    }
}

__global__ void k_deg(const int* __restrict__ col, float* __restrict__ deg, int ne) {
    int i = blockIdx.x * 256 + threadIdx.x;
    if (i < ne) atomicAdd(&deg[col[i]], 1.f);
}

__global__ void k_dinv(float* __restrict__ deg, int n) {  // in place: deg -> rsqrt(deg+1)
    int i = blockIdx.x * 256 + threadIdx.x;
    if (i < n) deg[i] = rsqrtf(deg[i] + 1.f);
}

// scatter-add: agg[col][f] += t[row][f] * dinv[row]*dinv[col]
// one thread per (edge, feature): 32 consecutive lanes -> 32 consecutive floats
// of one destination row => wave's atomics coalesce into 4 cache-line ops.
__global__ void k_agg(const int* __restrict__ row, const int* __restrict__ col,
                      const float* __restrict__ t, const float* __restrict__ dinv,
                      float* __restrict__ agg, int ne) {
    long idx = (long)blockIdx.x * 256 + threadIdx.x;
    if (idx >= (long)ne * 32) return;
    int e = (int)(idx >> 5), f = (int)idx & 31;
    int r = row[e], c = col[e];
    float coef = dinv[r] * dinv[c];
    atomicAdd(&agg[(long)c * 32 + f], t[(long)r * 32 + f] * coef);
}

// g += self-loop term + conv bias (float4)
__global__ void k_self_bias(float* __restrict__ agg, const float* __restrict__ t,
                            const float* __restrict__ dinv, const float* __restrict__ bias,
                            int n) {
    long idx = (long)blockIdx.x * 256 + threadIdx.x;
    if (idx >= (long)n * 8) return;
    int i = (int)(idx >> 3), fg = ((int)idx & 7) * 4;
    float d = dinv[i];
    float4 v = *(const float4*)&t[idx * 4];
    float4 b = *(const float4*)&bias[fg];
    float4* dst = (float4*)&agg[idx * 4];
    float4 a = *dst;
    a.x += v.x * d * d + b.x;
    a.y += v.y * d * d + b.y;
    a.z += v.z * d * d + b.z;
    a.w += v.w * d * d + b.w;
    *dst = a;
}

__global__ void k_affine_relu(const float* __restrict__ g, const float* __restrict__ A,
                              const float* __restrict__ B, float* __restrict__ h, long n32) {
    long idx = (long)blockIdx.x * 256 + threadIdx.x;
    if (idx >= (n32 >> 2)) return;
    int fg = ((int)idx & 7) * 4;
    float4 v = *(const float4*)&g[idx * 4];
    float4 a = *(const float4*)&A[fg];
    float4 b = *(const float4*)&B[fg];
    float4 r;
    r.x = fmaxf(a.x * v.x + b.x, 0.f);
    r.y = fmaxf(a.y * v.y + b.y, 0.f);
    r.z = fmaxf(a.z * v.z + b.z, 0.f);
    r.w = fmaxf(a.w * v.w + b.w, 0.f);
    *(float4*)&h[idx * 4] = r;
}

__global__ void k_mask(const int* __restrict__ pos2, int* __restrict__ mask, int p) {
    int i = blockIdx.x * 256 + threadIdx.x;
    if (i < p) mask[pos2[i]] = 1;
}

__global__ void k_count(const int* __restrict__ mask, int* __restrict__ cnt, int m) {
    __shared__ int sd[256];
    int idx = blockIdx.x * 256 + threadIdx.x;
    sd[threadIdx.x] = (idx < m) ? mask[idx] : 0;
    __syncthreads();
    for (int s = 128; s > 0; s >>= 1) {
        if (threadIdx.x < s) sd[threadIdx.x] += sd[threadIdx.x + s];
        __syncthreads();
    }
    if (threadIdx.x == 0) atomicAdd(cnt, sd[0]);
}

// z has only two distinct rows (mask 0/1); compute zc{0,1}[o] = z{0,1} @ c2_W[32:48]
__global__ void k_zcalc(const float* __restrict__ emb2, const float* __restrict__ w,
                        const float* __restrict__ b, const float* __restrict__ ms,
                        const int* __restrict__ cnt, const float* __restrict__ c2W,
                        float* __restrict__ zc0, float* __restrict__ zc1) {
    __shared__ float z0[16], z1[16];
    int t = threadIdx.x;  // 32 threads
    const float Mf = (float)M_PAIRS;
    if (t < 16) {
        float e0 = emb2[t], e1 = emb2[16 + t];
        float c1f = (float)(*cnt);
        float mean = (c1f * e1 + (Mf - c1f) * e0) / Mf;
        float c = ms[t] * mean;
        float d0 = e0 - c, d1 = e1 - c;
        float var = (c1f * d1 * d1 + (Mf - c1f) * d0 * d0) / Mf;
        float rs = rsqrtf(var + EPSF);
        z0[t] = w[t] * d0 * rs + b[t];
        z1[t] = w[t] * d1 * rs + b[t];
    }
    __syncthreads();
    float s0 = 0.f, s1 = 0.f;
    #pragma unroll
    for (int f = 0; f < 16; f++) {
        float wv = c2W[(32 + f) * 32 + t];
        s0 += z0[f] * wv;
        s1 += z1[f] * wv;
    }
    zc0[t] = s0;
    zc1[t] = s1;
}

// t2[j][fg..] = hw[a][fg..] + hw[b][fg..] + zc_{mask[j]}[fg..]
__global__ void k_t2(const float* __restrict__ hw, const int* __restrict__ pos1,
                     const int* __restrict__ mask, const float* __restrict__ zc0,
                     const float* __restrict__ zc1, float* __restrict__ t2, int m) {
    long idx = (long)blockIdx.x * 256 + threadIdx.x;
    if (idx >= (long)m * 8) return;
    int j = (int)(idx >> 3), fg = ((int)idx & 7) * 4;
    int a = pos1[2 * j], b = pos1[2 * j + 1];
    const float* zc = mask[j] ? zc1 : zc0;
    float4 va = *(const float4*)&hw[(long)a * 32 + fg];
    float4 vb = *(const float4*)&hw[(long)b * 32 + fg];
    float4 vz = *(const float4*)&zc[fg];
    float4 r;
    r.x = va.x + vb.x + vz.x;
    r.y = va.y + vb.y + vz.y;
    r.z = va.z + vb.z + vz.z;
    r.w = va.w + vb.w + vz.w;
    *(float4*)&t2[idx * 4] = r;
}

// out[k] = relu(A*g2[pos2[k]]+B) . predW + predb
__global__ void k_pred(const float* __restrict__ g2, const int* __restrict__ pos2,
                       const float* __restrict__ A, const float* __restrict__ B,
                       const float* __restrict__ predW, const float* __restrict__ predb,
                       float* __restrict__ out, int p) {
    int k = blockIdx.x * 256 + threadIdx.x;
    if (k >= p) return;
    int j = pos2[k];
    float s = predb[0];
    #pragma unroll
    for (int o = 0; o < 32; o++)
        s += fmaxf(A[o] * g2[(long)j * 32 + o] + B[o], 0.f) * predW[o];
    out[k] = s;
}

extern "C" void kernel_launch(void* const* d_in, const int* in_sizes, int n_in,
                              void* d_out, int out_size, void* d_ws, size_t ws_size,
                              hipStream_t stream) {
    const int*   x      = (const int*)d_in[0];
    const int*   e1row  = (const int*)d_in[1];
    const int*   e1col  = e1row + E1N;
    const int*   e2row  = (const int*)d_in[2];
    const int*   e2col  = e2row + E2N;
    const int*   pos1   = (const int*)d_in[3];
    const int*   pos2   = (const int*)d_in[4];
    const float* emb1   = (const float*)d_in[5];
    const float* gn0_w  = (const float*)d_in[6];
    const float* gn0_b  = (const float*)d_in[7];
    const float* gn0_ms = (const float*)d_in[8];
    const float* c1_W   = (const float*)d_in[9];
    const float* c1_b   = (const float*)d_in[10];
    const float* gn1_w  = (const float*)d_in[11];
    const float* gn1_b  = (const float*)d_in[12];
    const float* gn1_ms = (const float*)d_in[13];
    const float* emb2   = (const float*)d_in[14];
    const float* gn2_w  = (const float*)d_in[15];
    const float* gn2_b  = (const float*)d_in[16];
    const float* gn2_ms = (const float*)d_in[17];
    const float* c2_W   = (const float*)d_in[18];
    const float* c2_b   = (const float*)d_in[19];
    const float* gn3_w  = (const float*)d_in[20];
    const float* gn3_b  = (const float*)d_in[21];
    const float* gn3_ms = (const float*)d_in[22];
    const float* predW  = (const float*)d_in[23];
    const float* predb  = (const float*)d_in[24];
    float* out = (float*)d_out;

    // ---------------- workspace arena (floats) ----------------
    float* W = (float*)d_ws;
    const size_t N32 = (size_t)N_NODES * 32;   // 1,600,000
    const size_t M32 = (size_t)M_PAIRS * 32;   // 6,400,000
    float* e    = W;                 // N32   (reused as hw later)
    float* t    = e + N32;           // N32
    float* agg  = t + N32;           // N32
    float* h1   = agg + N32;         // N32
    float* t2   = h1 + N32;          // M32
    float* agg2 = t2 + M32;          // M32
    float* d1   = agg2 + M32;        // N
    float* d2   = d1 + N_NODES;      // M
    int*   mask = (int*)(d2 + M_PAIRS);  // M ints
    float* st   = (float*)(mask + M_PAIRS);  // S_TOTAL floats
    float* hw   = e;  // alias: e is dead after k_mm32 for conv1

    // ---------------- zero accumulators ----------------
    hipMemsetAsync(agg,  0, N32 * 4, stream);
    hipMemsetAsync(agg2, 0, M32 * 4, stream);
    hipMemsetAsync(d1,   0, N_NODES * 4, stream);
    hipMemsetAsync(d2,   0, M_PAIRS * 4, stream);
    hipMemsetAsync(mask, 0, M_PAIRS * 4, stream);
    hipMemsetAsync(st,   0, S_TOTAL * 4, stream);

    auto cdiv = [](long a, long b) { return (int)((a + b - 1) / b); };
    const float invN = 1.f / (float)N_NODES;
    const float invM = 1.f / (float)M_PAIRS;

    // ---- stage 0: embedding + gn0 stats ----
    k_embed_stats<<<RED_BLOCKS, 256, 0, stream>>>(emb1, x, e, st + S0_SUM, st + S0_SQ, N_NODES);
    k_deg<<<cdiv(E1N, 256), 256, 0, stream>>>(e1col, d1, E1N);
    k_dinv<<<cdiv(N_NODES, 256), 256, 0, stream>>>(d1, N_NODES);
    k_affine32<<<1, 32, 0, stream>>>(st + S0_SUM, st + S0_SQ, gn0_w, gn0_b, gn0_ms, invN,
                                     st + S_A0, st + S_B0);
    k_foldbias<<<1, 32, 0, stream>>>(st + S_B0, c1_W, st + S_B0ROW);

    // ---- conv1: t = gn0(e) @ c1_W ----
    k_mm32<<<cdiv(N_NODES, 8), 256, 0, stream>>>(e, c1_W, st + S_A0, st + S_B0ROW, t, N_NODES);
    k_agg<<<cdiv((long)E1N * 32, 256), 256, 0, stream>>>(e1row, e1col, t, d1, agg, E1N);
    k_self_bias<<<cdiv((long)N_NODES * 8, 256), 256, 0, stream>>>(agg, t, d1, c1_b, N_NODES);

    // ---- gn1 + relu -> h1 ----
    k_stats32<<<RED_BLOCKS, 256, 0, stream>>>(agg, st + S1_SUM, st + S1_SQ, (long)N32);
    k_affine32<<<1, 32, 0, stream>>>(st + S1_SUM, st + S1_SQ, gn1_w, gn1_b, gn1_ms, invN,
                                     st + S_A1, st + S_B1);
    k_affine_relu<<<cdiv((long)N32 / 4, 256), 256, 0, stream>>>(agg, st + S_A1, st + S_B1, h1, (long)N32);

    // ---- mask / z path ----
    k_mask<<<cdiv(P_OUT, 256), 256, 0, stream>>>(pos2, mask, P_OUT);
    k_count<<<cdiv(M_PAIRS, 256), 256, 0, stream>>>(mask, (int*)(st + S_CNT), M_PAIRS);
    k_zcalc<<<1, 32, 0, stream>>>(emb2, gn2_w, gn2_b, gn2_ms, (const int*)(st + S_CNT),
                                  c2_W, st + S_ZC0, st + S_ZC1);

    // ---- conv2 input: hw = h1 @ c2_W[0:32]; t2 = hw[a]+hw[b]+zc ----
    k_mm32<<<cdiv(N_NODES, 8), 256, 0, stream>>>(h1, c2_W, nullptr, nullptr, hw, N_NODES);
    k_t2<<<cdiv((long)M_PAIRS * 8, 256), 256, 0, stream>>>(hw, pos1, mask, st + S_ZC0, st + S_ZC1, t2, M_PAIRS);

    // ---- conv2 aggregation ----
    k_deg<<<cdiv(E2N, 256), 256, 0, stream>>>(e2col, d2, E2N);
    k_dinv<<<cdiv(M_PAIRS, 256), 256, 0, stream>>>(d2, M_PAIRS);
    k_agg<<<cdiv((long)E2N * 32, 256), 256, 0, stream>>>(e2row, e2col, t2, d2, agg2, E2N);
    k_self_bias<<<cdiv((long)M_PAIRS * 8, 256), 256, 0, stream>>>(agg2, t2, d2, c2_b, M_PAIRS);

    // ---- gn3 + relu + predict ----
    k_stats32<<<RED_BLOCKS, 256, 0, stream>>>(agg2, st + S3_SUM, st + S3_SQ, (long)M32);
    k_affine32<<<1, 32, 0, stream>>>(st + S3_SUM, st + S3_SQ, gn3_w, gn3_b, gn3_ms, invM,
                                     st + S_A3, st + S_B3);
    k_pred<<<cdiv(P_OUT, 256), 256, 0, stream>>>(agg2, pos2, st + S_A3, st + S_B3,
                                                 predW, predb, out, P_OUT);
}